// Round 1
// baseline (1224.144 us; speedup 1.0000x reference)
//
#include <hip/hip_runtime.h>
#include <hip/hip_bf16.h>
#include <stdint.h>

#define TOKS 16384
#define HDIM 2048
#define IDIM 1024
#define NEXP 8
#define TOPK 2
#define NPAIR (TOKS*TOPK)   // 32768

typedef __attribute__((ext_vector_type(4))) float f32x4;
typedef __attribute__((ext_vector_type(8))) __bf16 bf16x8;
typedef __attribute__((ext_vector_type(8))) unsigned short u16x8;

// async global->LDS, 16B per lane; LDS dest is wave-uniform base + lane*16
#define GLOAD_LDS16(gp, lp) \
  __builtin_amdgcn_global_load_lds((const __attribute__((address_space(1))) void*)(gp), \
                                   (__attribute__((address_space(3))) void*)(lp), 16, 0, 0)

__device__ __forceinline__ unsigned short f2bf(float f) {
  unsigned int u = __float_as_uint(f);
  u += 0x7FFF + ((u >> 16) & 1);   // RNE
  return (unsigned short)(u >> 16);
}

// ---------------- conversion: f32 -> bf16, 8 elems/thread ----------------
__global__ __launch_bounds__(256) void cvt_bf16(const float* __restrict__ src,
                                                unsigned short* __restrict__ dst,
                                                int n8) {
  int i = blockIdx.x * 256 + threadIdx.x;
  if (i >= n8) return;
  const float4* s = (const float4*)src + (size_t)i * 2;
  float4 a = s[0], b = s[1];
  u16x8 o;
  o[0] = f2bf(a.x); o[1] = f2bf(a.y); o[2] = f2bf(a.z); o[3] = f2bf(a.w);
  o[4] = f2bf(b.x); o[5] = f2bf(b.y); o[6] = f2bf(b.z); o[7] = f2bf(b.w);
  *((u16x8*)dst + i) = o;
}

// ---------------- routing ----------------
// ctrl layout (ints): [0..7]=counts, [8..15]=offsets, [16..23]=cursors
__global__ void route_count(const int* __restrict__ ert, int* __restrict__ ctrl) {
  int p = blockIdx.x * 256 + threadIdx.x;
  if (p < NPAIR) atomicAdd(&ctrl[ert[p]], 1);
}

__global__ void route_scan(int* __restrict__ ctrl) {
  if (blockIdx.x == 0 && threadIdx.x == 0) {
    int off = 0;
    for (int e = 0; e < NEXP; ++e) { ctrl[8 + e] = off; ctrl[16 + e] = off; off += ctrl[e]; }
  }
}

__global__ void route_scatter(const int* __restrict__ ert, const float* __restrict__ rw,
                              int* __restrict__ ctrl, int* __restrict__ ptok,
                              float* __restrict__ pcoef) {
  int p = blockIdx.x * 256 + threadIdx.x;
  if (p < NPAIR) {
    int e = ert[p];
    int pos = atomicAdd(&ctrl[16 + e], 1);
    ptok[pos] = p >> 1;          // TOPK = 2
    pcoef[pos] = rw[p];
  }
}

// ---------------- GEMM1: act = silu(x@Wg^T) * (x@Wu^T), bf16 out ----------------
// tile: 128 pair-rows x 64 act-cols; B-tile = 64 gate rows + 64 up rows; BK=64
__global__ __launch_bounds__(256) void gemm1(const unsigned short* __restrict__ xb,
                                             const unsigned short* __restrict__ w13b,
                                             const int* __restrict__ ctrl,
                                             const int* __restrict__ ptok,
                                             unsigned short* __restrict__ actb) {
  __shared__ __align__(16) unsigned short lA[128 * 64];
  __shared__ __align__(16) unsigned short lB[128 * 64];
  const int e    = blockIdx.z;
  const int Ne   = ctrl[e];
  const int base = ctrl[8 + e];
  const int n0   = blockIdx.x * 64;
  const int tid  = threadIdx.x;
  const int wid  = tid >> 6;
  const int lane = tid & 63;
  const int wr   = wid >> 1;     // row half (64 rows)
  const int wc   = wid & 1;      // col half (32 act cols)

  // B staging pointers (rb-independent)
  const unsigned short* gB[4];
  #pragma unroll
  for (int i = 0; i < 4; ++i) {
    int chunk = i * 4 + wid;            // 0..15 (1KB LDS chunks)
    int s = chunk * 64 + lane;          // 16B slot
    int nb = s >> 3;                    // B-tile row 0..127
    int c8 = s & 7;                     // 8-elem group in k
    int grow = (nb < 64) ? (n0 + nb) : (IDIM + n0 + (nb - 64));
    gB[i] = w13b + ((size_t)e * (2 * IDIM) + grow) * HDIM + c8 * 8;
  }

  for (int rb = blockIdx.y; rb * 128 < Ne; rb += gridDim.y) {
    const int row0 = rb * 128;
    // A gather pointers for this row block
    const unsigned short* gA[4];
    #pragma unroll
    for (int i = 0; i < 4; ++i) {
      int chunk = i * 4 + wid;
      int s = chunk * 64 + lane;
      int r = s >> 3;
      int c8 = s & 7;
      int rr = row0 + r; if (rr > Ne - 1) rr = Ne - 1;
      int t = ptok[base + rr];
      gA[i] = xb + (size_t)t * HDIM + c8 * 8;
    }

    f32x4 accg[4][2], accu[4][2];
    #pragma unroll
    for (int mi = 0; mi < 4; ++mi)
      #pragma unroll
      for (int ni = 0; ni < 2; ++ni) { accg[mi][ni] = (f32x4)(0.0f); accu[mi][ni] = (f32x4)(0.0f); }

    for (int kt = 0; kt < HDIM / 64; ++kt) {
      #pragma unroll
      for (int i = 0; i < 4; ++i)
        GLOAD_LDS16(gA[i] + kt * 64, (char*)lA + (i * 4 + wid) * 1024);
      #pragma unroll
      for (int i = 0; i < 4; ++i)
        GLOAD_LDS16(gB[i] + kt * 64, (char*)lB + (i * 4 + wid) * 1024);
      __syncthreads();
      #pragma unroll
      for (int ks = 0; ks < 2; ++ks) {
        const int ko = ks * 32 + (lane >> 4) * 8;
        bf16x8 af[4], bg[2], bu[2];
        #pragma unroll
        for (int mi = 0; mi < 4; ++mi)
          af[mi] = *(const bf16x8*)&lA[(wr * 64 + mi * 16 + (lane & 15)) * 64 + ko];
        #pragma unroll
        for (int ni = 0; ni < 2; ++ni) {
          bg[ni] = *(const bf16x8*)&lB[(wc * 32 + ni * 16 + (lane & 15)) * 64 + ko];
          bu[ni] = *(const bf16x8*)&lB[(64 + wc * 32 + ni * 16 + (lane & 15)) * 64 + ko];
        }
        #pragma unroll
        for (int mi = 0; mi < 4; ++mi)
          #pragma unroll
          for (int ni = 0; ni < 2; ++ni) {
            accg[mi][ni] = __builtin_amdgcn_mfma_f32_16x16x32_bf16(af[mi], bg[ni], accg[mi][ni], 0, 0, 0);
            accu[mi][ni] = __builtin_amdgcn_mfma_f32_16x16x32_bf16(af[mi], bu[ni], accu[mi][ni], 0, 0, 0);
          }
      }
      __syncthreads();
    }

    // epilogue: silu(g)*u -> bf16 act
    #pragma unroll
    for (int mi = 0; mi < 4; ++mi)
      #pragma unroll
      for (int ni = 0; ni < 2; ++ni) {
        int col = n0 + wc * 32 + ni * 16 + (lane & 15);
        #pragma unroll
        for (int j = 0; j < 4; ++j) {
          int r = wr * 64 + mi * 16 + (lane >> 4) * 4 + j;
          int rr = row0 + r;
          if (rr < Ne) {
            float g = accg[mi][ni][j], u = accu[mi][ni][j];
            float a = g / (1.0f + __expf(-g)) * u;
            actb[(size_t)(base + rr) * IDIM + col] = f2bf(a);
          }
        }
      }
    __syncthreads();
  }
}

// ---------------- GEMM2: out += coef * (act @ w2^T), atomic scatter ----------------
// tile: 128 pair-rows x 128 out-cols; BK=64
__global__ __launch_bounds__(256) void gemm2(const unsigned short* __restrict__ actb,
                                             const unsigned short* __restrict__ w2b,
                                             const int* __restrict__ ctrl,
                                             const int* __restrict__ ptok,
                                             const float* __restrict__ pcoef,
                                             float* __restrict__ out) {
  __shared__ __align__(16) unsigned short lA[128 * 64];
  __shared__ __align__(16) unsigned short lB[128 * 64];
  __shared__ int   ltok[128];
  __shared__ float lcoef[128];
  const int e    = blockIdx.z;
  const int Ne   = ctrl[e];
  const int base = ctrl[8 + e];
  const int n0   = blockIdx.x * 128;
  const int tid  = threadIdx.x;
  const int wid  = tid >> 6;
  const int lane = tid & 63;
  const int wr   = wid >> 1;
  const int wc   = wid & 1;

  const unsigned short* gB[4];
  #pragma unroll
  for (int i = 0; i < 4; ++i) {
    int chunk = i * 4 + wid;
    int s = chunk * 64 + lane;
    int nb = s >> 3;
    int c8 = s & 7;
    gB[i] = w2b + ((size_t)e * HDIM + n0 + nb) * IDIM + c8 * 8;
  }

  for (int rb = blockIdx.y; rb * 128 < Ne; rb += gridDim.y) {
    const int row0 = rb * 128;
    if (tid < 128) {
      int rr = row0 + tid;
      if (rr < Ne) { ltok[tid] = ptok[base + rr]; lcoef[tid] = pcoef[base + rr]; }
      else         { ltok[tid] = 0;               lcoef[tid] = 0.0f; }
    }
    const unsigned short* gA[4];
    #pragma unroll
    for (int i = 0; i < 4; ++i) {
      int chunk = i * 4 + wid;
      int s = chunk * 64 + lane;
      int r = s >> 3;
      int c8 = s & 7;
      int rr = row0 + r; if (rr > Ne - 1) rr = Ne - 1;
      gA[i] = actb + (size_t)(base + rr) * IDIM + c8 * 8;
    }

    f32x4 acc[4][4];
    #pragma unroll
    for (int mi = 0; mi < 4; ++mi)
      #pragma unroll
      for (int ni = 0; ni < 4; ++ni) acc[mi][ni] = (f32x4)(0.0f);

    for (int kt = 0; kt < IDIM / 64; ++kt) {
      #pragma unroll
      for (int i = 0; i < 4; ++i)
        GLOAD_LDS16(gA[i] + kt * 64, (char*)lA + (i * 4 + wid) * 1024);
      #pragma unroll
      for (int i = 0; i < 4; ++i)
        GLOAD_LDS16(gB[i] + kt * 64, (char*)lB + (i * 4 + wid) * 1024);
      __syncthreads();
      #pragma unroll
      for (int ks = 0; ks < 2; ++ks) {
        const int ko = ks * 32 + (lane >> 4) * 8;
        bf16x8 af[4], bf[4];
        #pragma unroll
        for (int mi = 0; mi < 4; ++mi)
          af[mi] = *(const bf16x8*)&lA[(wr * 64 + mi * 16 + (lane & 15)) * 64 + ko];
        #pragma unroll
        for (int ni = 0; ni < 4; ++ni)
          bf[ni] = *(const bf16x8*)&lB[(wc * 64 + ni * 16 + (lane & 15)) * 64 + ko];
        #pragma unroll
        for (int mi = 0; mi < 4; ++mi)
          #pragma unroll
          for (int ni = 0; ni < 4; ++ni)
            acc[mi][ni] = __builtin_amdgcn_mfma_f32_16x16x32_bf16(af[mi], bf[ni], acc[mi][ni], 0, 0, 0);
      }
      __syncthreads();
    }

    #pragma unroll
    for (int mi = 0; mi < 4; ++mi)
      #pragma unroll
      for (int ni = 0; ni < 4; ++ni) {
        int col = n0 + wc * 64 + ni * 16 + (lane & 15);
        #pragma unroll
        for (int j = 0; j < 4; ++j) {
          int r = wr * 64 + mi * 16 + (lane >> 4) * 4 + j;
          if (row0 + r < Ne) {
            float v = acc[mi][ni][j] * lcoef[r];
            atomicAdd(&out[(size_t)ltok[r] * HDIM + col], v);
          }
        }
      }
    __syncthreads();
  }
}

// ---------------- launcher ----------------
extern "C" void kernel_launch(void* const* d_in, const int* in_sizes, int n_in,
                              void* d_out, int out_size, void* d_ws, size_t ws_size,
                              hipStream_t stream) {
  const float* x   = (const float*)d_in[0];
  const int*   ert = (const int*)d_in[1];
  const float* rw  = (const float*)d_in[2];
  const float* w13 = (const float*)d_in[3];
  const float* w2  = (const float*)d_in[4];
  float* out = (float*)d_out;

  char* ws = (char*)d_ws;
  size_t off = 0;
  auto alloc = [&](size_t bytes) { char* p = ws + off; off += (bytes + 255) & ~255ULL; return p; };
  int*            ctrl  = (int*)           alloc(256);
  int*            ptok  = (int*)           alloc((size_t)NPAIR * 4);
  float*          pcoef = (float*)         alloc((size_t)NPAIR * 4);
  unsigned short* w13b  = (unsigned short*)alloc((size_t)NEXP * 2 * IDIM * HDIM * 2);
  unsigned short* w2b   = (unsigned short*)alloc((size_t)NEXP * HDIM * IDIM * 2);
  unsigned short* xb    = (unsigned short*)alloc((size_t)TOKS * HDIM * 2);
  unsigned short* actb  = (unsigned short*)alloc((size_t)NPAIR * IDIM * 2);

  hipMemsetAsync(ctrl, 0, 256, stream);
  hipMemsetAsync(out, 0, (size_t)out_size * 4, stream);

  cvt_bf16<<<(NEXP * 2 * IDIM * HDIM / 8) / 256, 256, 0, stream>>>(w13, w13b, NEXP * 2 * IDIM * HDIM / 8);
  cvt_bf16<<<(NEXP * HDIM * IDIM / 8) / 256, 256, 0, stream>>>(w2, w2b, NEXP * HDIM * IDIM / 8);
  cvt_bf16<<<(TOKS * HDIM / 8) / 256, 256, 0, stream>>>(x, xb, TOKS * HDIM / 8);

  route_count  <<<NPAIR / 256, 256, 0, stream>>>(ert, ctrl);
  route_scan   <<<1, 64, 0, stream>>>(ctrl);
  route_scatter<<<NPAIR / 256, 256, 0, stream>>>(ert, rw, ctrl, ptok, pcoef);

  gemm1<<<dim3(IDIM / 64, 48, NEXP), 256, 0, stream>>>(xb, w13b, ctrl, ptok, actb);
  gemm2<<<dim3(HDIM / 128, 48, NEXP), 256, 0, stream>>>(actb, w2b, ctrl, ptok, pcoef, out);
}

// Round 2
// 1143.984 us; speedup vs baseline: 1.0701x; 1.0701x over previous
//
#include <hip/hip_runtime.h>
#include <hip/hip_bf16.h>
#include <stdint.h>

#define TOKS 16384
#define HDIM 2048
#define IDIM 1024
#define NEXP 8
#define TOPK 2
#define NPAIR (TOKS*TOPK)   // 32768

typedef __attribute__((ext_vector_type(4))) float f32x4;
typedef __attribute__((ext_vector_type(8))) __bf16 bf16x8;
typedef __attribute__((ext_vector_type(8))) unsigned short u16x8;

// async global->LDS, 16B per lane; LDS dest is wave-uniform base + lane*16
#define GLOAD_LDS16(gp, lp) \
  __builtin_amdgcn_global_load_lds((const __attribute__((address_space(1))) void*)(gp), \
                                   (__attribute__((address_space(3))) void*)(lp), 16, 0, 0)

__device__ __forceinline__ unsigned short f2bf(float f) {
  unsigned int u = __float_as_uint(f);
  u += 0x7FFF + ((u >> 16) & 1);   // RNE
  return (unsigned short)(u >> 16);
}

// ---------------- conversion: f32 -> bf16, 8 elems/thread ----------------
__global__ __launch_bounds__(256) void cvt_bf16(const float* __restrict__ src,
                                                unsigned short* __restrict__ dst,
                                                int n8) {
  int i = blockIdx.x * 256 + threadIdx.x;
  if (i >= n8) return;
  const float4* s = (const float4*)src + (size_t)i * 2;
  float4 a = s[0], b = s[1];
  u16x8 o;
  o[0] = f2bf(a.x); o[1] = f2bf(a.y); o[2] = f2bf(a.z); o[3] = f2bf(a.w);
  o[4] = f2bf(b.x); o[5] = f2bf(b.y); o[6] = f2bf(b.z); o[7] = f2bf(b.w);
  *((u16x8*)dst + i) = o;
}

// ---------------- routing ----------------
// ctrl layout (ints): [0..7]=counts, [8..15]=offsets, [16..23]=cursors
__global__ void route_count(const int* __restrict__ ert, int* __restrict__ ctrl) {
  int p = blockIdx.x * 256 + threadIdx.x;
  if (p < NPAIR) atomicAdd(&ctrl[ert[p]], 1);
}

__global__ void route_scan(int* __restrict__ ctrl) {
  if (blockIdx.x == 0 && threadIdx.x == 0) {
    int off = 0;
    for (int e = 0; e < NEXP; ++e) { ctrl[8 + e] = off; ctrl[16 + e] = off; off += ctrl[e]; }
  }
}

__global__ void route_scatter(const int* __restrict__ ert, const float* __restrict__ rw,
                              int* __restrict__ ctrl, int* __restrict__ ptok,
                              float* __restrict__ pcoef) {
  int p = blockIdx.x * 256 + threadIdx.x;
  if (p < NPAIR) {
    int e = ert[p];
    int pos = atomicAdd(&ctrl[16 + e], 1);
    ptok[pos] = p >> 1;          // TOPK = 2
    pcoef[pos] = rw[p];
  }
}

// Swizzled LDS element offset for fragment reads: row-major [row][64] bf16,
// 8x 16B slots per row, slot index XORed with (row&7).
__device__ __forceinline__ int swz_off(int row, int j) {
  return row * 64 + ((j ^ (row & 7)) << 3);
}

// ---------------- GEMM1: act = silu(x@Wg^T) * (x@Wu^T), bf16 out ----------------
// tile: 128 pair-rows x 64 act-cols; B-tile = 64 gate rows + 64 up rows; BK=64
__global__ __launch_bounds__(256) void gemm1(const unsigned short* __restrict__ xb,
                                             const unsigned short* __restrict__ w13b,
                                             const int* __restrict__ ctrl,
                                             const int* __restrict__ ptok,
                                             unsigned short* __restrict__ actb) {
  __shared__ __align__(16) unsigned short lA[128 * 64];
  __shared__ __align__(16) unsigned short lB[128 * 64];
  const int e    = blockIdx.z;
  const int Ne   = ctrl[e];
  const int base = ctrl[8 + e];
  const int n0   = blockIdx.x * 64;
  const int tid  = threadIdx.x;
  const int wid  = tid >> 6;
  const int lane = tid & 63;
  const int wr   = wid >> 1;     // row half (64 rows)
  const int wc   = wid & 1;      // col half (32 act cols)

  // B staging pointers (rb-independent), source pre-swizzled (rule #21)
  const unsigned short* gB[4];
  #pragma unroll
  for (int i = 0; i < 4; ++i) {
    int chunk = i * 4 + wid;            // 0..15 (1KB LDS chunks)
    int s = chunk * 64 + lane;          // 16B slot
    int nb = s >> 3;                    // B-tile row 0..127
    int c8 = (s & 7) ^ (nb & 7);        // swizzled 8-elem group in k
    int grow = (nb < 64) ? (n0 + nb) : (IDIM + n0 + (nb - 64));
    gB[i] = w13b + ((size_t)e * (2 * IDIM) + grow) * HDIM + c8 * 8;
  }

  for (int rb = blockIdx.y; rb * 128 < Ne; rb += gridDim.y) {
    const int row0 = rb * 128;
    // A gather pointers for this row block (source pre-swizzled)
    const unsigned short* gA[4];
    #pragma unroll
    for (int i = 0; i < 4; ++i) {
      int chunk = i * 4 + wid;
      int s = chunk * 64 + lane;
      int r = s >> 3;
      int c8 = (s & 7) ^ (r & 7);
      int rr = row0 + r; if (rr > Ne - 1) rr = Ne - 1;
      int t = ptok[base + rr];
      gA[i] = xb + (size_t)t * HDIM + c8 * 8;
    }

    f32x4 accg[4][2], accu[4][2];
    #pragma unroll
    for (int mi = 0; mi < 4; ++mi)
      #pragma unroll
      for (int ni = 0; ni < 2; ++ni) { accg[mi][ni] = (f32x4)(0.0f); accu[mi][ni] = (f32x4)(0.0f); }

    for (int kt = 0; kt < HDIM / 64; ++kt) {
      #pragma unroll
      for (int i = 0; i < 4; ++i)
        GLOAD_LDS16(gA[i] + kt * 64, (char*)lA + (i * 4 + wid) * 1024);
      #pragma unroll
      for (int i = 0; i < 4; ++i)
        GLOAD_LDS16(gB[i] + kt * 64, (char*)lB + (i * 4 + wid) * 1024);
      __syncthreads();
      #pragma unroll
      for (int ks = 0; ks < 2; ++ks) {
        const int j = ks * 4 + (lane >> 4);   // 16B slot index in row
        bf16x8 af[4], bg[2], bu[2];
        #pragma unroll
        for (int mi = 0; mi < 4; ++mi)
          af[mi] = *(const bf16x8*)&lA[swz_off(wr * 64 + mi * 16 + (lane & 15), j)];
        #pragma unroll
        for (int ni = 0; ni < 2; ++ni) {
          bg[ni] = *(const bf16x8*)&lB[swz_off(wc * 32 + ni * 16 + (lane & 15), j)];
          bu[ni] = *(const bf16x8*)&lB[swz_off(64 + wc * 32 + ni * 16 + (lane & 15), j)];
        }
        #pragma unroll
        for (int mi = 0; mi < 4; ++mi)
          #pragma unroll
          for (int ni = 0; ni < 2; ++ni) {
            accg[mi][ni] = __builtin_amdgcn_mfma_f32_16x16x32_bf16(af[mi], bg[ni], accg[mi][ni], 0, 0, 0);
            accu[mi][ni] = __builtin_amdgcn_mfma_f32_16x16x32_bf16(af[mi], bu[ni], accu[mi][ni], 0, 0, 0);
          }
      }
      __syncthreads();
    }

    // epilogue: silu(g)*u -> bf16 act
    #pragma unroll
    for (int mi = 0; mi < 4; ++mi)
      #pragma unroll
      for (int ni = 0; ni < 2; ++ni) {
        int col = n0 + wc * 32 + ni * 16 + (lane & 15);
        #pragma unroll
        for (int j = 0; j < 4; ++j) {
          int r = wr * 64 + mi * 16 + (lane >> 4) * 4 + j;
          int rr = row0 + r;
          if (rr < Ne) {
            float g = accg[mi][ni][j], u = accu[mi][ni][j];
            float a = g / (1.0f + __expf(-g)) * u;
            actb[(size_t)(base + rr) * IDIM + col] = f2bf(a);
          }
        }
      }
    __syncthreads();
  }
}

// ---------------- GEMM2: out += coef * (act @ w2^T), atomic scatter ----------------
// tile: 128 pair-rows x 128 out-cols; BK=64
__global__ __launch_bounds__(256) void gemm2(const unsigned short* __restrict__ actb,
                                             const unsigned short* __restrict__ w2b,
                                             const int* __restrict__ ctrl,
                                             const int* __restrict__ ptok,
                                             const float* __restrict__ pcoef,
                                             float* __restrict__ out) {
  __shared__ __align__(16) unsigned short lA[128 * 64];
  __shared__ __align__(16) unsigned short lB[128 * 64];
  __shared__ int   ltok[128];
  __shared__ float lcoef[128];
  const int e    = blockIdx.z;
  const int Ne   = ctrl[e];
  const int base = ctrl[8 + e];
  const int n0   = blockIdx.x * 128;
  const int tid  = threadIdx.x;
  const int wid  = tid >> 6;
  const int lane = tid & 63;
  const int wr   = wid >> 1;
  const int wc   = wid & 1;

  const unsigned short* gB[4];
  #pragma unroll
  for (int i = 0; i < 4; ++i) {
    int chunk = i * 4 + wid;
    int s = chunk * 64 + lane;
    int nb = s >> 3;
    int c8 = (s & 7) ^ (nb & 7);
    gB[i] = w2b + ((size_t)e * HDIM + n0 + nb) * IDIM + c8 * 8;
  }

  for (int rb = blockIdx.y; rb * 128 < Ne; rb += gridDim.y) {
    const int row0 = rb * 128;
    if (tid < 128) {
      int rr = row0 + tid;
      if (rr < Ne) { ltok[tid] = ptok[base + rr]; lcoef[tid] = pcoef[base + rr]; }
      else         { ltok[tid] = 0;               lcoef[tid] = 0.0f; }
    }
    const unsigned short* gA[4];
    #pragma unroll
    for (int i = 0; i < 4; ++i) {
      int chunk = i * 4 + wid;
      int s = chunk * 64 + lane;
      int r = s >> 3;
      int c8 = (s & 7) ^ (r & 7);
      int rr = row0 + r; if (rr > Ne - 1) rr = Ne - 1;
      gA[i] = actb + (size_t)(base + rr) * IDIM + c8 * 8;
    }

    f32x4 acc[4][4];
    #pragma unroll
    for (int mi = 0; mi < 4; ++mi)
      #pragma unroll
      for (int ni = 0; ni < 4; ++ni) acc[mi][ni] = (f32x4)(0.0f);

    for (int kt = 0; kt < IDIM / 64; ++kt) {
      #pragma unroll
      for (int i = 0; i < 4; ++i)
        GLOAD_LDS16(gA[i] + kt * 64, (char*)lA + (i * 4 + wid) * 1024);
      #pragma unroll
      for (int i = 0; i < 4; ++i)
        GLOAD_LDS16(gB[i] + kt * 64, (char*)lB + (i * 4 + wid) * 1024);
      __syncthreads();
      #pragma unroll
      for (int ks = 0; ks < 2; ++ks) {
        const int j = ks * 4 + (lane >> 4);
        bf16x8 af[4], bfr[4];
        #pragma unroll
        for (int mi = 0; mi < 4; ++mi)
          af[mi] = *(const bf16x8*)&lA[swz_off(wr * 64 + mi * 16 + (lane & 15), j)];
        #pragma unroll
        for (int ni = 0; ni < 4; ++ni)
          bfr[ni] = *(const bf16x8*)&lB[swz_off(wc * 64 + ni * 16 + (lane & 15), j)];
        #pragma unroll
        for (int mi = 0; mi < 4; ++mi)
          #pragma unroll
          for (int ni = 0; ni < 4; ++ni)
            acc[mi][ni] = __builtin_amdgcn_mfma_f32_16x16x32_bf16(af[mi], bfr[ni], acc[mi][ni], 0, 0, 0);
      }
      __syncthreads();
    }

    #pragma unroll
    for (int mi = 0; mi < 4; ++mi)
      #pragma unroll
      for (int ni = 0; ni < 4; ++ni) {
        int col = n0 + wc * 64 + ni * 16 + (lane & 15);
        #pragma unroll
        for (int j = 0; j < 4; ++j) {
          int r = wr * 64 + mi * 16 + (lane >> 4) * 4 + j;
          if (row0 + r < Ne) {
            float v = acc[mi][ni][j] * lcoef[r];
            atomicAdd(&out[(size_t)ltok[r] * HDIM + col], v);
          }
        }
      }
    __syncthreads();
  }
}

// ---------------- launcher ----------------
extern "C" void kernel_launch(void* const* d_in, const int* in_sizes, int n_in,
                              void* d_out, int out_size, void* d_ws, size_t ws_size,
                              hipStream_t stream) {
  const float* x   = (const float*)d_in[0];
  const int*   ert = (const int*)d_in[1];
  const float* rw  = (const float*)d_in[2];
  const float* w13 = (const float*)d_in[3];
  const float* w2  = (const float*)d_in[4];
  float* out = (float*)d_out;

  char* ws = (char*)d_ws;
  size_t off = 0;
  auto alloc = [&](size_t bytes) { char* p = ws + off; off += (bytes + 255) & ~255ULL; return p; };
  int*            ctrl  = (int*)           alloc(256);
  int*            ptok  = (int*)           alloc((size_t)NPAIR * 4);
  float*          pcoef = (float*)         alloc((size_t)NPAIR * 4);
  unsigned short* w13b  = (unsigned short*)alloc((size_t)NEXP * 2 * IDIM * HDIM * 2);
  unsigned short* w2b   = (unsigned short*)alloc((size_t)NEXP * HDIM * IDIM * 2);
  unsigned short* xb    = (unsigned short*)alloc((size_t)TOKS * HDIM * 2);
  unsigned short* actb  = (unsigned short*)alloc((size_t)NPAIR * IDIM * 2);

  hipMemsetAsync(ctrl, 0, 256, stream);
  hipMemsetAsync(out, 0, (size_t)out_size * 4, stream);

  cvt_bf16<<<(NEXP * 2 * IDIM * HDIM / 8) / 256, 256, 0, stream>>>(w13, w13b, NEXP * 2 * IDIM * HDIM / 8);
  cvt_bf16<<<(NEXP * HDIM * IDIM / 8) / 256, 256, 0, stream>>>(w2, w2b, NEXP * HDIM * IDIM / 8);
  cvt_bf16<<<(TOKS * HDIM / 8) / 256, 256, 0, stream>>>(x, xb, TOKS * HDIM / 8);

  route_count  <<<NPAIR / 256, 256, 0, stream>>>(ert, ctrl);
  route_scan   <<<1, 64, 0, stream>>>(ctrl);
  route_scatter<<<NPAIR / 256, 256, 0, stream>>>(ert, rw, ctrl, ptok, pcoef);

  gemm1<<<dim3(IDIM / 64, 48, NEXP), 256, 0, stream>>>(xb, w13b, ctrl, ptok, actb);
  gemm2<<<dim3(HDIM / 128, 48, NEXP), 256, 0, stream>>>(actb, w2b, ctrl, ptok, pcoef, out);
}